// Round 6
// baseline (1869.558 us; speedup 1.0000x reference)
//
#include <hip/hip_runtime.h>
#include <hip/hip_bf16.h>

// SGConv (K=2) on MI355X.
// R1: dst-CSR + gather hops. R2: coalesced matmul loads. R4: MFMA matmul.
// R5: bucket-partitioned graph build + LDS-accumulated hops.
//   - k_scan (280us, 1-block serial) and k_scatter (282us, 15x write
//     amplification from cross-XCD partial sectors) are DELETED.
//   - Edges partitioned into 256-node buckets with per-block exclusive
//     ranges (full-sector writes); hops accumulate in LDS per bucket.

#define TPB 256
#define ETILE 8192                 // edges per partition block

typedef __attribute__((ext_vector_type(8))) short short8v;   // bf16x8
typedef __attribute__((ext_vector_type(4))) float f32x4;

__device__ inline short f2bf(float f) {            // RNE f32->bf16
    unsigned u = __float_as_uint(f);
    unsigned r = (u + 0x7fffu + ((u >> 16) & 1u)) >> 16;
    return (short)r;
}

// ---- per-bucket edge histogram (bucket = dst>>8) -----------------------
__global__ __launch_bounds__(TPB) void k_bhist(
    const int* __restrict__ dst, int* __restrict__ bcnt, int E, int nb) {
    __shared__ int h[512];
    int t = threadIdx.x;
    for (int i = t; i < nb; i += TPB) h[i] = 0;
    __syncthreads();
    int e0 = blockIdx.x * ETILE;
    for (int i = t; i < ETILE; i += TPB) {
        int e = e0 + i;
        if (e < E) atomicAdd(&h[dst[e] >> 8], 1);
    }
    __syncthreads();
    for (int i = t; i < nb; i += TPB)
        if (h[i]) atomicAdd(&bcnt[i], h[i]);
}

// ---- 391-entry exclusive scan -> boff, bcur (single block) -------------
__global__ __launch_bounds__(512) void k_boff(
    const int* __restrict__ bcnt, int* __restrict__ boff,
    int* __restrict__ bcur, int nb) {
    __shared__ int s[512];
    int t = threadIdx.x;
    int own = (t < nb) ? bcnt[t] : 0;
    s[t] = own;
    __syncthreads();
    for (int off = 1; off < 512; off <<= 1) {
        int v = (t >= off) ? s[t - off] : 0;
        __syncthreads();
        s[t] += v;
        __syncthreads();
    }
    if (t < nb) {
        int ex = s[t] - own;
        boff[t] = ex;
        bcur[t] = ex;
        if (t == nb - 1) boff[nb] = s[t];
    }
}

// ---- block-aggregated bucket partition ---------------------------------
// Each block: LDS-hist its 8192-edge tile, reserve EXCLUSIVE contiguous
// per-bucket ranges (one global atomicAdd per bucket), write packed
// (dlow<<20)|src into its own ranges -> full-sector writebacks.
__global__ __launch_bounds__(TPB) void k_part(
    const int* __restrict__ src, const int* __restrict__ dst,
    int* __restrict__ bcur, int* __restrict__ pairs, int E, int nb) {
    __shared__ int stash[ETILE];
    __shared__ int hist[512], base[512], lcur[512];
    int t = threadIdx.x;
    for (int i = t; i < nb; i += TPB) hist[i] = 0;
    __syncthreads();
    int e0 = blockIdx.x * ETILE;
    for (int i = t; i < ETILE; i += TPB) {
        int e = e0 + i;
        int d = (e < E) ? dst[e] : -1;
        stash[i] = d;
        if (d >= 0) atomicAdd(&hist[d >> 8], 1);
    }
    __syncthreads();
    for (int i = t; i < nb; i += TPB) {
        base[i] = hist[i] ? atomicAdd(&bcur[i], hist[i]) : 0;
        lcur[i] = 0;
    }
    __syncthreads();
    for (int i = t; i < ETILE; i += TPB) {
        int d = stash[i];
        if (d >= 0) {
            int b = d >> 8;
            int pos = base[b] + atomicAdd(&lcur[b], 1);
            pairs[pos] = ((d & 255) << 20) | src[e0 + i];   // src < 2^20
        }
    }
}

// ---- per-bucket in-degree -> dinv --------------------------------------
__global__ __launch_bounds__(TPB) void k_dinvb(
    const int* __restrict__ pairs, const int* __restrict__ boff,
    float* __restrict__ dinv, int N) {
    __shared__ int h[256];
    int b = blockIdx.x, t = threadIdx.x;
    h[t] = 0;
    __syncthreads();
    int beg = boff[b], end = boff[b + 1];
    for (int j = beg + t; j < end; j += TPB)
        atomicAdd(&h[pairs[j] >> 20], 1);
    __syncthreads();
    int d = (b << 8) + t;
    if (d < N) dinv[d] = rsqrtf((float)(h[t] + 1));   // +1 self-loop
}

// ---- W (40x512 f32) -> Wb (48x512 bf16, rows 40..47 zero) --------------
__global__ void k_wconv(const float* __restrict__ W, short* __restrict__ Wb) {
    int idx = blockIdx.x * TPB + threadIdx.x;    // 0..24575
    int c = idx >> 9, k = idx & 511;
    float v = (c < 40) ? W[c * 512 + k] : 0.f;
    Wb[idx] = f2bf(v);
}

// ---- z0 = dinv .* (x @ W^T) via MFMA bf16 ------------------------------
__global__ __launch_bounds__(TPB) void k_matmul_mfma(
    const float* __restrict__ x, const short* __restrict__ Wb,
    const float* __restrict__ dinv, float* __restrict__ z, int N) {
    int wid  = threadIdx.x >> 6;
    int lane = threadIdx.x & 63;
    int rbase = blockIdx.x * 64 + wid * 16;
    if (rbase >= N) return;
    int arow   = rbase + (lane & 15);
    int aclamp = min(arow, N - 1);
    int koff   = (lane >> 4) * 8;
    const float* xrow = x + (size_t)aclamp * 512 + koff;
    const short* wb   = Wb + (lane & 15) * 512 + koff;

    f32x4 acc0 = {0.f,0.f,0.f,0.f}, acc1 = {0.f,0.f,0.f,0.f}, acc2 = {0.f,0.f,0.f,0.f};
    for (int ks = 0; ks < 16; ++ks) {
        int k0 = ks * 32;
        float4 f0 = *reinterpret_cast<const float4*>(xrow + k0);
        float4 f1 = *reinterpret_cast<const float4*>(xrow + k0 + 4);
        short8v a;
        a[0] = f2bf(f0.x); a[1] = f2bf(f0.y); a[2] = f2bf(f0.z); a[3] = f2bf(f0.w);
        a[4] = f2bf(f1.x); a[5] = f2bf(f1.y); a[6] = f2bf(f1.z); a[7] = f2bf(f1.w);
        short8v b0 = *reinterpret_cast<const short8v*>(wb + k0);
        short8v b1 = *reinterpret_cast<const short8v*>(wb + 16 * 512 + k0);
        short8v b2 = *reinterpret_cast<const short8v*>(wb + 32 * 512 + k0);
        acc0 = __builtin_amdgcn_mfma_f32_16x16x32_bf16(a, b0, acc0, 0, 0, 0);
        acc1 = __builtin_amdgcn_mfma_f32_16x16x32_bf16(a, b1, acc1, 0, 0, 0);
        acc2 = __builtin_amdgcn_mfma_f32_16x16x32_bf16(a, b2, acc2, 0, 0, 0);
    }
    int col = lane & 15;
    int rw  = rbase + (lane >> 4) * 4;
#pragma unroll
    for (int reg = 0; reg < 4; ++reg) {
        int r = rw + reg;
        if (r < N) {
            float di = dinv[r];
            z[(size_t)r * 40 + col]      = di * acc0[reg];
            z[(size_t)r * 40 + 16 + col] = di * acc1[reg];
            if (col < 8)
                z[(size_t)r * 40 + 32 + col] = di * acc2[reg];
        }
    }
}

// ---- hop, LDS-accumulated per bucket -----------------------------------
// zout[d] = dinv[d]^P * (zin[d] + sum_{s -> d} zin[s]), d in [256b, 256b+256)
template <int P>
__global__ __launch_bounds__(TPB) void k_hop_lds(
    const int* __restrict__ pairs, const int* __restrict__ boff,
    const float* __restrict__ dinv, const float* __restrict__ zin,
    float* __restrict__ zout, int N) {
    __shared__ float acc[256 * 41];     // pad 41: conflict-free columns
    __shared__ float dsc[256];
    int b = blockIdx.x, t = threadIdx.x;
    for (int i = t; i < 256 * 41; i += TPB) acc[i] = 0.f;
    __syncthreads();
    int beg = boff[b], end = boff[b + 1];
    for (int j = beg + t; j < end; j += TPB) {
        int u = pairs[j];
        int dl = u >> 20;
        const float* zr = zin + (size_t)(u & 0xFFFFF) * 40;
        float* ar = &acc[dl * 41];
#pragma unroll
        for (int c4 = 0; c4 < 10; ++c4) {
            float4 v = *reinterpret_cast<const float4*>(zr + c4 * 4);
            atomicAdd(ar + c4 * 4 + 0, v.x);
            atomicAdd(ar + c4 * 4 + 1, v.y);
            atomicAdd(ar + c4 * 4 + 2, v.z);
            atomicAdd(ar + c4 * 4 + 3, v.w);
        }
    }
    {
        int d = (b << 8) + t;
        float dd = (d < N) ? dinv[d] : 0.f;
        dsc[t] = (P == 2) ? dd * dd : dd;
    }
    __syncthreads();
    int b0 = (b << 8);
    // coalesced finalize over the bucket's 2560 float4 slots
#pragma unroll
    for (int j = 0; j < 10; ++j) {
        int e = t + TPB * j;            // 0..2559
        int node = e / 10;
        int c4 = e - node * 10;
        int d = b0 + node;
        if (d < N) {
            float4 zv = *reinterpret_cast<const float4*>(zin + (size_t)d * 40 + c4 * 4);
            float sc = dsc[node];
            const float* ar = &acc[node * 41 + c4 * 4];
            float4 o = make_float4(sc * (ar[0] + zv.x), sc * (ar[1] + zv.y),
                                   sc * (ar[2] + zv.z), sc * (ar[3] + zv.w));
            *reinterpret_cast<float4*>(zout + (size_t)d * 40 + c4 * 4) = o;
        }
    }
}

// ---- log_softmax rows, in place on d_out, + bias -----------------------
__global__ __launch_bounds__(TPB) void k_logsoftmax(
    float* __restrict__ out, const float* __restrict__ b, int N) {
    int r = blockIdx.x * TPB + threadIdx.x;
    if (r >= N) return;
    float4* rowp = reinterpret_cast<float4*>(out + (size_t)r * 40);
    float v[40];
    float m = -1e30f;
#pragma unroll
    for (int c4 = 0; c4 < 10; ++c4) {
        float4 t = rowp[c4];
        v[c4*4+0] = t.x + b[c4*4+0];
        v[c4*4+1] = t.y + b[c4*4+1];
        v[c4*4+2] = t.z + b[c4*4+2];
        v[c4*4+3] = t.w + b[c4*4+3];
    }
#pragma unroll
    for (int c = 0; c < 40; ++c) m = fmaxf(m, v[c]);
    float sum = 0.f;
#pragma unroll
    for (int c = 0; c < 40; ++c) sum += __expf(v[c] - m);
    float lse = m + __logf(sum);
#pragma unroll
    for (int c4 = 0; c4 < 10; ++c4)
        rowp[c4] = make_float4(v[c4*4+0]-lse, v[c4*4+1]-lse, v[c4*4+2]-lse, v[c4*4+3]-lse);
}

extern "C" void kernel_launch(void* const* d_in, const int* in_sizes, int n_in,
                              void* d_out, int out_size, void* d_ws, size_t ws_size,
                              hipStream_t stream) {
    const float* x  = (const float*)d_in[0];
    const int*   ei = (const int*)d_in[1];
    const float* W  = (const float*)d_in[2];
    const float* b  = (const float*)d_in[3];
    float* out = (float*)d_out;

    const int N = in_sizes[0] / 512;     // 100000
    const int E = in_sizes[1] / 2;       // 3200000
    const int* src = ei;                 // edge_index[0]
    const int* dst = ei + E;             // edge_index[1]
    const int nb = (N + 255) >> 8;       // 391 buckets

    // workspace: z1 [N*40 f32] | pairs [E i32] | bcnt [nb] | boff [nb+1] | bcur [nb] | dinv [N f32]
    float* z1    = (float*)d_ws;
    int*   pairs = (int*)(z1 + (size_t)N * 40);
    int*   bcnt  = pairs + E;
    int*   boff  = bcnt + nb;
    int*   bcur  = boff + nb + 1;
    float* dinv  = (float*)(bcur + nb);
    float* z0    = out;                  // stage z0 in d_out (rewritten by hop2)
    // Wb (48x512 bf16 = 48KB) aliases the TAIL of z1 (dead until hop1 writes)
    short* Wb    = (short*)(z1 + (size_t)N * 40) - 48 * 512;

    hipMemsetAsync(bcnt, 0, (size_t)nb * sizeof(int), stream);

    int gN = (N + TPB - 1) / TPB;
    int gT = (E + ETILE - 1) / ETILE;    // 391 edge tiles
    int gM = (N + 63) / 64;

    k_wconv<<<(48 * 512) / TPB, TPB, 0, stream>>>(W, Wb);
    k_bhist<<<gT, TPB, 0, stream>>>(dst, bcnt, E, nb);
    k_boff<<<1, 512, 0, stream>>>(bcnt, boff, bcur, nb);
    k_part<<<gT, TPB, 0, stream>>>(src, dst, bcur, pairs, E, nb);
    k_dinvb<<<nb, TPB, 0, stream>>>(pairs, boff, dinv, N);

    k_matmul_mfma<<<gM, TPB, 0, stream>>>(x, Wb, dinv, z0, N);

    k_hop_lds<2><<<nb, TPB, 0, stream>>>(pairs, boff, dinv, z0, z1, N);   // hop 1
    k_hop_lds<1><<<nb, TPB, 0, stream>>>(pairs, boff, dinv, z1, out, N);  // hop 2

    k_logsoftmax<<<gN, TPB, 0, stream>>>(out, b, N);
}

// Round 7
// 400.208 us; speedup vs baseline: 4.6715x; 4.6715x over previous
//
#include <hip/hip_runtime.h>
#include <hip/hip_bf16.h>

// SGConv (K=2) on MI355X.
// R4: MFMA matmul + gather hops (good). R5: bucket build (good) but
//     LDS-atomic hops REGRESSED (391 blocks, 128M ds-atomics, 857us).
// R6: bucket build -> per-bucket counting sort -> dst-sorted CSR, then
//     R4's register-accumulating gather hops. scan/scatter/hist deleted.

#define TPB 256
#define ETILE 8192                 // edges per partition block

typedef __attribute__((ext_vector_type(8))) short short8v;   // bf16x8
typedef __attribute__((ext_vector_type(4))) float f32x4;

__device__ inline short f2bf(float f) {            // RNE f32->bf16
    unsigned u = __float_as_uint(f);
    unsigned r = (u + 0x7fffu + ((u >> 16) & 1u)) >> 16;
    return (short)r;
}

// ---- per-bucket edge histogram (bucket = dst>>8) -----------------------
__global__ __launch_bounds__(TPB) void k_bhist(
    const int* __restrict__ dst, int* __restrict__ bcnt, int E, int nb) {
    __shared__ int h[512];
    int t = threadIdx.x;
    for (int i = t; i < nb; i += TPB) h[i] = 0;
    __syncthreads();
    int e0 = blockIdx.x * ETILE;
    for (int i = t; i < ETILE; i += TPB) {
        int e = e0 + i;
        if (e < E) atomicAdd(&h[dst[e] >> 8], 1);
    }
    __syncthreads();
    for (int i = t; i < nb; i += TPB)
        if (h[i]) atomicAdd(&bcnt[i], h[i]);
}

// ---- 391-entry exclusive scan -> boff, bcur (single block, trivial) ----
__global__ __launch_bounds__(512) void k_boff(
    const int* __restrict__ bcnt, int* __restrict__ boff,
    int* __restrict__ bcur, int nb) {
    __shared__ int s[512];
    int t = threadIdx.x;
    int own = (t < nb) ? bcnt[t] : 0;
    s[t] = own;
    __syncthreads();
    for (int off = 1; off < 512; off <<= 1) {
        int v = (t >= off) ? s[t - off] : 0;
        __syncthreads();
        s[t] += v;
        __syncthreads();
    }
    if (t < nb) {
        int ex = s[t] - own;
        boff[t] = ex;
        bcur[t] = ex;
        if (t == nb - 1) boff[nb] = s[t];
    }
}

// ---- block-aggregated bucket partition ---------------------------------
// Each block: LDS-hist its 8192-edge tile, reserve EXCLUSIVE contiguous
// per-bucket ranges (one global atomicAdd per bucket), write packed
// (dlow<<20)|src into its own ranges -> full-sector writebacks.
__global__ __launch_bounds__(TPB) void k_part(
    const int* __restrict__ src, const int* __restrict__ dst,
    int* __restrict__ bcur, int* __restrict__ pairs, int E, int nb) {
    __shared__ int stash[ETILE];
    __shared__ int hist[512], base[512], lcur[512];
    int t = threadIdx.x;
    for (int i = t; i < nb; i += TPB) hist[i] = 0;
    __syncthreads();
    int e0 = blockIdx.x * ETILE;
    for (int i = t; i < ETILE; i += TPB) {
        int e = e0 + i;
        int d = (e < E) ? dst[e] : -1;
        stash[i] = d;
        if (d >= 0) atomicAdd(&hist[d >> 8], 1);
    }
    __syncthreads();
    for (int i = t; i < nb; i += TPB) {
        base[i] = hist[i] ? atomicAdd(&bcur[i], hist[i]) : 0;
        lcur[i] = 0;
    }
    __syncthreads();
    for (int i = t; i < ETILE; i += TPB) {
        int d = stash[i];
        if (d >= 0) {
            int b = d >> 8;
            int pos = base[b] + atomicAdd(&lcur[b], 1);
            pairs[pos] = ((d & 255) << 20) | src[e0 + i];   // src < 2^20
        }
    }
}

// ---- per-bucket counting sort: pairs -> dst-sorted csr -----------------
// Also emits row_ptr[node] and dinv[node]. Block b owns nodes [256b,256b+256)
// and writes only csr[boff[b]..boff[b+1]) -> exclusive, L2-assembled sectors.
__global__ __launch_bounds__(TPB) void k_sort(
    const int* __restrict__ pairs, const int* __restrict__ boff,
    int* __restrict__ csr, int* __restrict__ row_ptr, float* __restrict__ dinv,
    int N, int nb) {
    __shared__ int hist[256], excl[256], lcur[256];
    int b = blockIdx.x, t = threadIdx.x;
    hist[t] = 0;
    __syncthreads();
    int beg = boff[b], end = boff[b + 1];
    for (int j = beg + t; j < end; j += TPB)
        atomicAdd(&hist[pairs[j] >> 20], 1);
    __syncthreads();
    int own = hist[t];
    excl[t] = own;
    __syncthreads();
    for (int off = 1; off < 256; off <<= 1) {
        int v = (t >= off) ? excl[t - off] : 0;
        __syncthreads();
        excl[t] += v;
        __syncthreads();
    }
    int node = (b << 8) + t;
    if (node < N) {
        row_ptr[node] = beg + excl[t] - own;   // global exclusive offset
        dinv[node] = rsqrtf((float)(own + 1)); // +1 self-loop
    }
    lcur[t] = 0;
    __syncthreads();
    for (int j = beg + t; j < end; j += TPB) {
        int u = pairs[j];
        int dl = u >> 20;
        int pos = beg + (excl[dl] - hist[dl]) + atomicAdd(&lcur[dl], 1);
        csr[pos] = u & 0xFFFFF;
    }
    if (b == nb - 1 && t == 0) row_ptr[N] = end;
}

// ---- W (40x512 f32) -> Wb (48x512 bf16, rows 40..47 zero) --------------
__global__ void k_wconv(const float* __restrict__ W, short* __restrict__ Wb) {
    int idx = blockIdx.x * TPB + threadIdx.x;    // 0..24575
    int c = idx >> 9, k = idx & 511;
    float v = (c < 40) ? W[c * 512 + k] : 0.f;
    Wb[idx] = f2bf(v);
}

// ---- z0 = dinv .* (x @ W^T) via MFMA bf16 ------------------------------
__global__ __launch_bounds__(TPB) void k_matmul_mfma(
    const float* __restrict__ x, const short* __restrict__ Wb,
    const float* __restrict__ dinv, float* __restrict__ z, int N) {
    int wid  = threadIdx.x >> 6;
    int lane = threadIdx.x & 63;
    int rbase = blockIdx.x * 64 + wid * 16;
    if (rbase >= N) return;
    int arow   = rbase + (lane & 15);
    int aclamp = min(arow, N - 1);
    int koff   = (lane >> 4) * 8;
    const float* xrow = x + (size_t)aclamp * 512 + koff;
    const short* wb   = Wb + (lane & 15) * 512 + koff;

    f32x4 acc0 = {0.f,0.f,0.f,0.f}, acc1 = {0.f,0.f,0.f,0.f}, acc2 = {0.f,0.f,0.f,0.f};
    for (int ks = 0; ks < 16; ++ks) {
        int k0 = ks * 32;
        float4 f0 = *reinterpret_cast<const float4*>(xrow + k0);
        float4 f1 = *reinterpret_cast<const float4*>(xrow + k0 + 4);
        short8v a;
        a[0] = f2bf(f0.x); a[1] = f2bf(f0.y); a[2] = f2bf(f0.z); a[3] = f2bf(f0.w);
        a[4] = f2bf(f1.x); a[5] = f2bf(f1.y); a[6] = f2bf(f1.z); a[7] = f2bf(f1.w);
        short8v b0 = *reinterpret_cast<const short8v*>(wb + k0);
        short8v b1 = *reinterpret_cast<const short8v*>(wb + 16 * 512 + k0);
        short8v b2 = *reinterpret_cast<const short8v*>(wb + 32 * 512 + k0);
        acc0 = __builtin_amdgcn_mfma_f32_16x16x32_bf16(a, b0, acc0, 0, 0, 0);
        acc1 = __builtin_amdgcn_mfma_f32_16x16x32_bf16(a, b1, acc1, 0, 0, 0);
        acc2 = __builtin_amdgcn_mfma_f32_16x16x32_bf16(a, b2, acc2, 0, 0, 0);
    }
    int col = lane & 15;
    int rw  = rbase + (lane >> 4) * 4;
#pragma unroll
    for (int reg = 0; reg < 4; ++reg) {
        int r = rw + reg;
        if (r < N) {
            float di = dinv[r];
            z[(size_t)r * 40 + col]      = di * acc0[reg];
            z[(size_t)r * 40 + 16 + col] = di * acc1[reg];
            if (col < 8)
                z[(size_t)r * 40 + 32 + col] = di * acc2[reg];
        }
    }
}

// ---- gather hop: out[d] = dinv[d]^P * (z[d] + sum_{s in N(d)} z[s]) ----
// 10 threads per node, one float4 chunk each; register accumulation.
template <int P>
__global__ __launch_bounds__(TPB) void k_hop_csr(
    const int* __restrict__ csr, const int* __restrict__ row_ptr,
    const float* __restrict__ dinv, const float* __restrict__ zin,
    float* __restrict__ out, int N) {
    int t = blockIdx.x * TPB + threadIdx.x;
    int node = t / 10;
    int c4 = t - node * 10;
    if (node >= N) return;
    const float4* Z = reinterpret_cast<const float4*>(zin);
    float4 acc = Z[node * 10 + c4];            // self-loop term (z includes dinv)
    int beg = row_ptr[node];
    int end = row_ptr[node + 1];
    for (int j = beg; j < end; ++j) {
        int s = csr[j];                        // broadcast across the 10 lanes
        float4 v = Z[s * 10 + c4];
        acc.x += v.x; acc.y += v.y; acc.z += v.z; acc.w += v.w;
    }
    float dd = dinv[node];
    float sc = (P == 2) ? dd * dd : dd;
    reinterpret_cast<float4*>(out)[node * 10 + c4] =
        make_float4(sc*acc.x, sc*acc.y, sc*acc.z, sc*acc.w);
}

// ---- log_softmax rows, in place on d_out, + bias -----------------------
__global__ __launch_bounds__(TPB) void k_logsoftmax(
    float* __restrict__ out, const float* __restrict__ b, int N) {
    int r = blockIdx.x * TPB + threadIdx.x;
    if (r >= N) return;
    float4* rowp = reinterpret_cast<float4*>(out + (size_t)r * 40);
    float v[40];
    float m = -1e30f;
#pragma unroll
    for (int c4 = 0; c4 < 10; ++c4) {
        float4 t = rowp[c4];
        v[c4*4+0] = t.x + b[c4*4+0];
        v[c4*4+1] = t.y + b[c4*4+1];
        v[c4*4+2] = t.z + b[c4*4+2];
        v[c4*4+3] = t.w + b[c4*4+3];
    }
#pragma unroll
    for (int c = 0; c < 40; ++c) m = fmaxf(m, v[c]);
    float sum = 0.f;
#pragma unroll
    for (int c = 0; c < 40; ++c) sum += __expf(v[c] - m);
    float lse = m + __logf(sum);
#pragma unroll
    for (int c4 = 0; c4 < 10; ++c4)
        rowp[c4] = make_float4(v[c4*4+0]-lse, v[c4*4+1]-lse, v[c4*4+2]-lse, v[c4*4+3]-lse);
}

extern "C" void kernel_launch(void* const* d_in, const int* in_sizes, int n_in,
                              void* d_out, int out_size, void* d_ws, size_t ws_size,
                              hipStream_t stream) {
    const float* x  = (const float*)d_in[0];
    const int*   ei = (const int*)d_in[1];
    const float* W  = (const float*)d_in[2];
    const float* b  = (const float*)d_in[3];
    float* out = (float*)d_out;

    const int N = in_sizes[0] / 512;     // 100000
    const int E = in_sizes[1] / 2;       // 3200000
    const int* src = ei;                 // edge_index[0]
    const int* dst = ei + E;             // edge_index[1]
    const int nb = (N + 255) >> 8;       // 391 buckets

    // workspace: z1 [N*40 f32] | csr [E] | bcnt [nb] | boff [nb+1] | bcur [nb]
    //            | row_ptr [N+1] | dinv [N]
    // pairs (E ints = 12.8MB) aliases z1's HEAD; Wb (48KB) aliases z1's TAIL.
    // Both are dead by the time hop1 writes z1.
    float* z1      = (float*)d_ws;
    int*   csr     = (int*)(z1 + (size_t)N * 40);
    int*   bcnt    = csr + E;
    int*   boff    = bcnt + nb;
    int*   bcur    = boff + nb + 1;
    int*   row_ptr = bcur + nb;
    float* dinv    = (float*)(row_ptr + N + 1);
    int*   pairs   = (int*)z1;
    short* Wb      = (short*)(z1 + (size_t)N * 40) - 48 * 512;
    float* z0      = out;                // stage z0 in d_out (rewritten by hop2)

    hipMemsetAsync(bcnt, 0, (size_t)nb * sizeof(int), stream);

    int gN = (N + TPB - 1) / TPB;
    int gT = (E + ETILE - 1) / ETILE;    // 391 edge tiles
    int gM = (N + 63) / 64;
    int gH = (N * 10 + TPB - 1) / TPB;

    k_wconv<<<(48 * 512) / TPB, TPB, 0, stream>>>(W, Wb);
    k_bhist<<<gT, TPB, 0, stream>>>(dst, bcnt, E, nb);
    k_boff<<<1, 512, 0, stream>>>(bcnt, boff, bcur, nb);
    k_part<<<gT, TPB, 0, stream>>>(src, dst, bcur, pairs, E, nb);
    k_sort<<<nb, TPB, 0, stream>>>(pairs, boff, csr, row_ptr, dinv, N, nb);

    k_matmul_mfma<<<gM, TPB, 0, stream>>>(x, Wb, dinv, z0, N);

    k_hop_csr<2><<<gH, TPB, 0, stream>>>(csr, row_ptr, dinv, z0, z1, N);   // hop 1
    k_hop_csr<1><<<gH, TPB, 0, stream>>>(csr, row_ptr, dinv, z1, out, N);  // hop 2

    k_logsoftmax<<<gN, TPB, 0, stream>>>(out, b, N);
}

// Round 8
// 352.132 us; speedup vs baseline: 5.3092x; 1.1365x over previous
//
#include <hip/hip_runtime.h>
#include <hip/hip_bf16.h>

// SGConv (K=2) on MI355X.
// R4: MFMA matmul + gather hops. R6: bucket build + per-bucket counting sort.
// R7: (a) in-graph hipMemsetAsync -> tiny zero kernel (rocclr fill anomaly),
//     (b) bf16 z-tables: hops gather 80B/node-row instead of 160B (halves
//     L2/L3 gather traffic), f32 accumulation, hop2 emits f32.

#define TPB 256
#define ETILE 8192                 // edges per partition block

typedef __attribute__((ext_vector_type(8))) short short8v;   // bf16x8
typedef __attribute__((ext_vector_type(4))) float f32x4;

__device__ inline short f2bf(float f) {            // RNE f32->bf16
    unsigned u = __float_as_uint(f);
    unsigned r = (u + 0x7fffu + ((u >> 16) & 1u)) >> 16;
    return (short)r;
}
__device__ inline float bf2f(short s) {
    return __uint_as_float(((unsigned)(unsigned short)s) << 16);
}

// ---- zero bcnt (replaces rocclr fillBuffer in the graph) ---------------
__global__ void k_zero(int* __restrict__ p, int n) {
    int i = threadIdx.x;
    if (i < n) p[i] = 0;
}

// ---- per-bucket edge histogram (bucket = dst>>8) -----------------------
__global__ __launch_bounds__(TPB) void k_bhist(
    const int* __restrict__ dst, int* __restrict__ bcnt, int E, int nb) {
    __shared__ int h[512];
    int t = threadIdx.x;
    for (int i = t; i < nb; i += TPB) h[i] = 0;
    __syncthreads();
    int e0 = blockIdx.x * ETILE;
    for (int i = t; i < ETILE; i += TPB) {
        int e = e0 + i;
        if (e < E) atomicAdd(&h[dst[e] >> 8], 1);
    }
    __syncthreads();
    for (int i = t; i < nb; i += TPB)
        if (h[i]) atomicAdd(&bcnt[i], h[i]);
}

// ---- 391-entry exclusive scan -> boff, bcur (single block) -------------
__global__ __launch_bounds__(512) void k_boff(
    const int* __restrict__ bcnt, int* __restrict__ boff,
    int* __restrict__ bcur, int nb) {
    __shared__ int s[512];
    int t = threadIdx.x;
    int own = (t < nb) ? bcnt[t] : 0;
    s[t] = own;
    __syncthreads();
    for (int off = 1; off < 512; off <<= 1) {
        int v = (t >= off) ? s[t - off] : 0;
        __syncthreads();
        s[t] += v;
        __syncthreads();
    }
    if (t < nb) {
        int ex = s[t] - own;
        boff[t] = ex;
        bcur[t] = ex;
        if (t == nb - 1) boff[nb] = s[t];
    }
}

// ---- block-aggregated bucket partition ---------------------------------
__global__ __launch_bounds__(TPB) void k_part(
    const int* __restrict__ src, const int* __restrict__ dst,
    int* __restrict__ bcur, int* __restrict__ pairs, int E, int nb) {
    __shared__ int stash[ETILE];
    __shared__ int hist[512], base[512], lcur[512];
    int t = threadIdx.x;
    for (int i = t; i < nb; i += TPB) hist[i] = 0;
    __syncthreads();
    int e0 = blockIdx.x * ETILE;
    for (int i = t; i < ETILE; i += TPB) {
        int e = e0 + i;
        int d = (e < E) ? dst[e] : -1;
        stash[i] = d;
        if (d >= 0) atomicAdd(&hist[d >> 8], 1);
    }
    __syncthreads();
    for (int i = t; i < nb; i += TPB) {
        base[i] = hist[i] ? atomicAdd(&bcur[i], hist[i]) : 0;
        lcur[i] = 0;
    }
    __syncthreads();
    for (int i = t; i < ETILE; i += TPB) {
        int d = stash[i];
        if (d >= 0) {
            int b = d >> 8;
            int pos = base[b] + atomicAdd(&lcur[b], 1);
            pairs[pos] = ((d & 255) << 20) | src[e0 + i];   // src < 2^20
        }
    }
}

// ---- per-bucket counting sort: pairs -> dst-sorted csr + row_ptr + dinv
__global__ __launch_bounds__(TPB) void k_sort(
    const int* __restrict__ pairs, const int* __restrict__ boff,
    int* __restrict__ csr, int* __restrict__ row_ptr, float* __restrict__ dinv,
    int N, int nb) {
    __shared__ int hist[256], excl[256], lcur[256];
    int b = blockIdx.x, t = threadIdx.x;
    hist[t] = 0;
    __syncthreads();
    int beg = boff[b], end = boff[b + 1];
    for (int j = beg + t; j < end; j += TPB)
        atomicAdd(&hist[pairs[j] >> 20], 1);
    __syncthreads();
    int own = hist[t];
    excl[t] = own;
    __syncthreads();
    for (int off = 1; off < 256; off <<= 1) {
        int v = (t >= off) ? excl[t - off] : 0;
        __syncthreads();
        excl[t] += v;
        __syncthreads();
    }
    int node = (b << 8) + t;
    if (node < N) {
        row_ptr[node] = beg + excl[t] - own;   // global exclusive offset
        dinv[node] = rsqrtf((float)(own + 1)); // +1 self-loop
    }
    lcur[t] = 0;
    __syncthreads();
    for (int j = beg + t; j < end; j += TPB) {
        int u = pairs[j];
        int dl = u >> 20;
        int pos = beg + (excl[dl] - hist[dl]) + atomicAdd(&lcur[dl], 1);
        csr[pos] = u & 0xFFFFF;
    }
    if (b == nb - 1 && t == 0) row_ptr[N] = end;
}

// ---- W (40x512 f32) -> Wb (48x512 bf16, rows 40..47 zero) --------------
__global__ void k_wconv(const float* __restrict__ W, short* __restrict__ Wb) {
    int idx = blockIdx.x * TPB + threadIdx.x;    // 0..24575
    int c = idx >> 9, k = idx & 511;
    float v = (c < 40) ? W[c * 512 + k] : 0.f;
    Wb[idx] = f2bf(v);
}

// ---- z0 = bf16( dinv .* (x @ W^T) ) via MFMA bf16 ----------------------
__global__ __launch_bounds__(TPB) void k_matmul_mfma(
    const float* __restrict__ x, const short* __restrict__ Wb,
    const float* __restrict__ dinv, short* __restrict__ z, int N) {
    int wid  = threadIdx.x >> 6;
    int lane = threadIdx.x & 63;
    int rbase = blockIdx.x * 64 + wid * 16;
    if (rbase >= N) return;
    int arow   = rbase + (lane & 15);
    int aclamp = min(arow, N - 1);
    int koff   = (lane >> 4) * 8;
    const float* xrow = x + (size_t)aclamp * 512 + koff;
    const short* wb   = Wb + (lane & 15) * 512 + koff;

    f32x4 acc0 = {0.f,0.f,0.f,0.f}, acc1 = {0.f,0.f,0.f,0.f}, acc2 = {0.f,0.f,0.f,0.f};
    for (int ks = 0; ks < 16; ++ks) {
        int k0 = ks * 32;
        float4 f0 = *reinterpret_cast<const float4*>(xrow + k0);
        float4 f1 = *reinterpret_cast<const float4*>(xrow + k0 + 4);
        short8v a;
        a[0] = f2bf(f0.x); a[1] = f2bf(f0.y); a[2] = f2bf(f0.z); a[3] = f2bf(f0.w);
        a[4] = f2bf(f1.x); a[5] = f2bf(f1.y); a[6] = f2bf(f1.z); a[7] = f2bf(f1.w);
        short8v b0 = *reinterpret_cast<const short8v*>(wb + k0);
        short8v b1 = *reinterpret_cast<const short8v*>(wb + 16 * 512 + k0);
        short8v b2 = *reinterpret_cast<const short8v*>(wb + 32 * 512 + k0);
        acc0 = __builtin_amdgcn_mfma_f32_16x16x32_bf16(a, b0, acc0, 0, 0, 0);
        acc1 = __builtin_amdgcn_mfma_f32_16x16x32_bf16(a, b1, acc1, 0, 0, 0);
        acc2 = __builtin_amdgcn_mfma_f32_16x16x32_bf16(a, b2, acc2, 0, 0, 0);
    }
    int col = lane & 15;
    int rw  = rbase + (lane >> 4) * 4;
#pragma unroll
    for (int reg = 0; reg < 4; ++reg) {
        int r = rw + reg;
        if (r < N) {
            float di = dinv[r];
            z[(size_t)r * 40 + col]      = f2bf(di * acc0[reg]);
            z[(size_t)r * 40 + 16 + col] = f2bf(di * acc1[reg]);
            if (col < 8)
                z[(size_t)r * 40 + 32 + col] = f2bf(di * acc2[reg]);
        }
    }
}

// ---- gather hop on bf16 z: 5 lanes/node, bf16x8 chunk each -------------
// acc_f32 = zin[d] + sum_{s->d} zin[s];  P==2: zout=bf16(dinv^2*acc) (hop1)
//                                        P==1: out_f32=dinv*acc      (hop2)
template <int P>
__global__ __launch_bounds__(TPB) void k_hop_bf16(
    const int* __restrict__ csr, const int* __restrict__ row_ptr,
    const float* __restrict__ dinv, const short* __restrict__ zin,
    short* __restrict__ zout_bf, float* __restrict__ zout_f32, int N) {
    int t = blockIdx.x * TPB + threadIdx.x;
    int node = t / 5;
    int c8 = t - node * 5;
    if (node >= N) return;
    const short8v* Z = reinterpret_cast<const short8v*>(zin);
    short8v sv = Z[node * 5 + c8];             // self-loop term
    float acc[8];
#pragma unroll
    for (int k = 0; k < 8; ++k) acc[k] = bf2f(sv[k]);
    int beg = row_ptr[node];
    int end = row_ptr[node + 1];
    for (int j = beg; j < end; ++j) {
        int s = csr[j];                        // broadcast across the 5 lanes
        short8v v = Z[s * 5 + c8];
#pragma unroll
        for (int k = 0; k < 8; ++k) acc[k] += bf2f(v[k]);
    }
    float dd = dinv[node];
    if (P == 2) {
        float sc = dd * dd;
        short8v o;
#pragma unroll
        for (int k = 0; k < 8; ++k) o[k] = f2bf(sc * acc[k]);
        reinterpret_cast<short8v*>(zout_bf)[node * 5 + c8] = o;
    } else {
        float* op = zout_f32 + (size_t)node * 40 + c8 * 8;
        *reinterpret_cast<float4*>(op)     = make_float4(dd*acc[0], dd*acc[1], dd*acc[2], dd*acc[3]);
        *reinterpret_cast<float4*>(op + 4) = make_float4(dd*acc[4], dd*acc[5], dd*acc[6], dd*acc[7]);
    }
}

// ---- log_softmax rows, in place on d_out, + bias -----------------------
__global__ __launch_bounds__(TPB) void k_logsoftmax(
    float* __restrict__ out, const float* __restrict__ b, int N) {
    int r = blockIdx.x * TPB + threadIdx.x;
    if (r >= N) return;
    float4* rowp = reinterpret_cast<float4*>(out + (size_t)r * 40);
    float v[40];
    float m = -1e30f;
#pragma unroll
    for (int c4 = 0; c4 < 10; ++c4) {
        float4 t = rowp[c4];
        v[c4*4+0] = t.x + b[c4*4+0];
        v[c4*4+1] = t.y + b[c4*4+1];
        v[c4*4+2] = t.z + b[c4*4+2];
        v[c4*4+3] = t.w + b[c4*4+3];
    }
#pragma unroll
    for (int c = 0; c < 40; ++c) m = fmaxf(m, v[c]);
    float sum = 0.f;
#pragma unroll
    for (int c = 0; c < 40; ++c) sum += __expf(v[c] - m);
    float lse = m + __logf(sum);
#pragma unroll
    for (int c4 = 0; c4 < 10; ++c4)
        rowp[c4] = make_float4(v[c4*4+0]-lse, v[c4*4+1]-lse, v[c4*4+2]-lse, v[c4*4+3]-lse);
}

extern "C" void kernel_launch(void* const* d_in, const int* in_sizes, int n_in,
                              void* d_out, int out_size, void* d_ws, size_t ws_size,
                              hipStream_t stream) {
    const float* x  = (const float*)d_in[0];
    const int*   ei = (const int*)d_in[1];
    const float* W  = (const float*)d_in[2];
    const float* b  = (const float*)d_in[3];
    float* out = (float*)d_out;

    const int N = in_sizes[0] / 512;     // 100000
    const int E = in_sizes[1] / 2;       // 3200000
    const int* src = ei;                 // edge_index[0]
    const int* dst = ei + E;             // edge_index[1]
    const int nb = (N + 255) >> 8;       // 391 buckets

    // workspace (no aliasing): z0b [N*40 bf16] | z1b [N*40 bf16] | csr [E]
    //   | pairs [E] | bcnt [nb] | boff [nb+1] | bcur [nb] | row_ptr [N+1]
    //   | dinv [N] | Wb [48*512 bf16]     (~42 MB total)
    short* z0b     = (short*)d_ws;
    short* z1b     = z0b + (size_t)N * 40;
    int*   csr     = (int*)(z1b + (size_t)N * 40);
    int*   pairs   = csr + E;
    int*   bcnt    = pairs + E;
    int*   boff    = bcnt + nb;
    int*   bcur    = boff + nb + 1;
    int*   row_ptr = bcur + nb;
    float* dinv    = (float*)(row_ptr + N + 1);
    short* Wb      = (short*)(dinv + N);

    int gN = (N + TPB - 1) / TPB;
    int gT = (E + ETILE - 1) / ETILE;    // 391 edge tiles
    int gM = (N + 63) / 64;
    int gH = (N * 5 + TPB - 1) / TPB;

    k_zero<<<1, 512, 0, stream>>>(bcnt, nb);
    k_wconv<<<(48 * 512) / TPB, TPB, 0, stream>>>(W, Wb);
    k_bhist<<<gT, TPB, 0, stream>>>(dst, bcnt, E, nb);
    k_boff<<<1, 512, 0, stream>>>(bcnt, boff, bcur, nb);
    k_part<<<gT, TPB, 0, stream>>>(src, dst, bcur, pairs, E, nb);
    k_sort<<<nb, TPB, 0, stream>>>(pairs, boff, csr, row_ptr, dinv, N, nb);

    k_matmul_mfma<<<gM, TPB, 0, stream>>>(x, Wb, dinv, z0b, N);

    k_hop_bf16<2><<<gH, TPB, 0, stream>>>(csr, row_ptr, dinv, z0b, z1b, nullptr, N); // hop 1
    k_hop_bf16<1><<<gH, TPB, 0, stream>>>(csr, row_ptr, dinv, z1b, nullptr, out, N); // hop 2

    k_logsoftmax<<<gN, TPB, 0, stream>>>(out, b, N);
}

// Round 9
// 315.913 us; speedup vs baseline: 5.9180x; 1.1147x over previous
//
#include <hip/hip_runtime.h>
#include <hip/hip_bf16.h>

// SGConv (K=2) on MI355X.
// R4: MFMA matmul. R6: bucket build + counting sort -> CSR gather hops.
// R7: bf16 z-tables (halved gather traffic).
// R8: hops are LATENCY-bound -> unroll gather x4 (4 loads in flight);
//     fuse bias+log_softmax into hop2 (shfl reduce over 5-lane groups);
//     fold bcnt zeroing into k_wconv. 10 -> 8 launches.

#define TPB 256
#define ETILE 8192                 // edges per partition block

typedef __attribute__((ext_vector_type(8))) short short8v;   // bf16x8
typedef __attribute__((ext_vector_type(4))) float f32x4;

__device__ inline short f2bf(float f) {            // RNE f32->bf16
    unsigned u = __float_as_uint(f);
    unsigned r = (u + 0x7fffu + ((u >> 16) & 1u)) >> 16;
    return (short)r;
}
__device__ inline float bf2f(short s) {
    return __uint_as_float(((unsigned)(unsigned short)s) << 16);
}

// ---- per-bucket edge histogram (bucket = dst>>8) -----------------------
__global__ __launch_bounds__(TPB) void k_bhist(
    const int* __restrict__ dst, int* __restrict__ bcnt, int E, int nb) {
    __shared__ int h[512];
    int t = threadIdx.x;
    for (int i = t; i < nb; i += TPB) h[i] = 0;
    __syncthreads();
    int e0 = blockIdx.x * ETILE;
    for (int i = t; i < ETILE; i += TPB) {
        int e = e0 + i;
        if (e < E) atomicAdd(&h[dst[e] >> 8], 1);
    }
    __syncthreads();
    for (int i = t; i < nb; i += TPB)
        if (h[i]) atomicAdd(&bcnt[i], h[i]);
}

// ---- 391-entry exclusive scan -> boff, bcur (single block) -------------
__global__ __launch_bounds__(512) void k_boff(
    const int* __restrict__ bcnt, int* __restrict__ boff,
    int* __restrict__ bcur, int nb) {
    __shared__ int s[512];
    int t = threadIdx.x;
    int own = (t < nb) ? bcnt[t] : 0;
    s[t] = own;
    __syncthreads();
    for (int off = 1; off < 512; off <<= 1) {
        int v = (t >= off) ? s[t - off] : 0;
        __syncthreads();
        s[t] += v;
        __syncthreads();
    }
    if (t < nb) {
        int ex = s[t] - own;
        boff[t] = ex;
        bcur[t] = ex;
        if (t == nb - 1) boff[nb] = s[t];
    }
}

// ---- block-aggregated bucket partition ---------------------------------
__global__ __launch_bounds__(TPB) void k_part(
    const int* __restrict__ src, const int* __restrict__ dst,
    int* __restrict__ bcur, int* __restrict__ pairs, int E, int nb) {
    __shared__ int stash[ETILE];
    __shared__ int hist[512], base[512], lcur[512];
    int t = threadIdx.x;
    for (int i = t; i < nb; i += TPB) hist[i] = 0;
    __syncthreads();
    int e0 = blockIdx.x * ETILE;
    for (int i = t; i < ETILE; i += TPB) {
        int e = e0 + i;
        int d = (e < E) ? dst[e] : -1;
        stash[i] = d;
        if (d >= 0) atomicAdd(&hist[d >> 8], 1);
    }
    __syncthreads();
    for (int i = t; i < nb; i += TPB) {
        base[i] = hist[i] ? atomicAdd(&bcur[i], hist[i]) : 0;
        lcur[i] = 0;
    }
    __syncthreads();
    for (int i = t; i < ETILE; i += TPB) {
        int d = stash[i];
        if (d >= 0) {
            int b = d >> 8;
            int pos = base[b] + atomicAdd(&lcur[b], 1);
            pairs[pos] = ((d & 255) << 20) | src[e0 + i];   // src < 2^20
        }
    }
}

// ---- per-bucket counting sort: pairs -> dst-sorted csr + row_ptr + dinv
__global__ __launch_bounds__(TPB) void k_sort(
    const int* __restrict__ pairs, const int* __restrict__ boff,
    int* __restrict__ csr, int* __restrict__ row_ptr, float* __restrict__ dinv,
    int N, int nb) {
    __shared__ int hist[256], excl[256], lcur[256];
    int b = blockIdx.x, t = threadIdx.x;
    hist[t] = 0;
    __syncthreads();
    int beg = boff[b], end = boff[b + 1];
    for (int j = beg + t; j < end; j += TPB)
        atomicAdd(&hist[pairs[j] >> 20], 1);
    __syncthreads();
    int own = hist[t];
    excl[t] = own;
    __syncthreads();
    for (int off = 1; off < 256; off <<= 1) {
        int v = (t >= off) ? excl[t - off] : 0;
        __syncthreads();
        excl[t] += v;
        __syncthreads();
    }
    int node = (b << 8) + t;
    if (node < N) {
        row_ptr[node] = beg + excl[t] - own;   // global exclusive offset
        dinv[node] = rsqrtf((float)(own + 1)); // +1 self-loop
    }
    lcur[t] = 0;
    __syncthreads();
    for (int j = beg + t; j < end; j += TPB) {
        int u = pairs[j];
        int dl = u >> 20;
        int pos = beg + (excl[dl] - hist[dl]) + atomicAdd(&lcur[dl], 1);
        csr[pos] = u & 0xFFFFF;
    }
    if (b == nb - 1 && t == 0) row_ptr[N] = end;
}

// ---- W -> Wb (48x512 bf16) and (block 0) zero bcnt ---------------------
__global__ void k_wconv(const float* __restrict__ W, short* __restrict__ Wb,
                        int* __restrict__ bcnt, int nb) {
    if (blockIdx.x == 0)
        for (int i = threadIdx.x; i < nb; i += TPB) bcnt[i] = 0;
    int idx = blockIdx.x * TPB + threadIdx.x;    // 0..24575
    int c = idx >> 9, k = idx & 511;
    float v = (c < 40) ? W[c * 512 + k] : 0.f;
    Wb[idx] = f2bf(v);
}

// ---- z0 = bf16( dinv .* (x @ W^T) ) via MFMA bf16 ----------------------
__global__ __launch_bounds__(TPB) void k_matmul_mfma(
    const float* __restrict__ x, const short* __restrict__ Wb,
    const float* __restrict__ dinv, short* __restrict__ z, int N) {
    int wid  = threadIdx.x >> 6;
    int lane = threadIdx.x & 63;
    int rbase = blockIdx.x * 64 + wid * 16;
    if (rbase >= N) return;
    int arow   = rbase + (lane & 15);
    int aclamp = min(arow, N - 1);
    int koff   = (lane >> 4) * 8;
    const float* xrow = x + (size_t)aclamp * 512 + koff;
    const short* wb   = Wb + (lane & 15) * 512 + koff;

    f32x4 acc0 = {0.f,0.f,0.f,0.f}, acc1 = {0.f,0.f,0.f,0.f}, acc2 = {0.f,0.f,0.f,0.f};
    for (int ks = 0; ks < 16; ++ks) {
        int k0 = ks * 32;
        float4 f0 = *reinterpret_cast<const float4*>(xrow + k0);
        float4 f1 = *reinterpret_cast<const float4*>(xrow + k0 + 4);
        short8v a;
        a[0] = f2bf(f0.x); a[1] = f2bf(f0.y); a[2] = f2bf(f0.z); a[3] = f2bf(f0.w);
        a[4] = f2bf(f1.x); a[5] = f2bf(f1.y); a[6] = f2bf(f1.z); a[7] = f2bf(f1.w);
        short8v b0 = *reinterpret_cast<const short8v*>(wb + k0);
        short8v b1 = *reinterpret_cast<const short8v*>(wb + 16 * 512 + k0);
        short8v b2 = *reinterpret_cast<const short8v*>(wb + 32 * 512 + k0);
        acc0 = __builtin_amdgcn_mfma_f32_16x16x32_bf16(a, b0, acc0, 0, 0, 0);
        acc1 = __builtin_amdgcn_mfma_f32_16x16x32_bf16(a, b1, acc1, 0, 0, 0);
        acc2 = __builtin_amdgcn_mfma_f32_16x16x32_bf16(a, b2, acc2, 0, 0, 0);
    }
    int col = lane & 15;
    int rw  = rbase + (lane >> 4) * 4;
#pragma unroll
    for (int reg = 0; reg < 4; ++reg) {
        int r = rw + reg;
        if (r < N) {
            float di = dinv[r];
            z[(size_t)r * 40 + col]      = f2bf(di * acc0[reg]);
            z[(size_t)r * 40 + 16 + col] = f2bf(di * acc1[reg]);
            if (col < 8)
                z[(size_t)r * 40 + 32 + col] = f2bf(di * acc2[reg]);
        }
    }
}

// ---- shared gather body: acc[8] += sum_{s in csr[beg..end)} zin[s] -----
__device__ inline void gather_acc(
    const short8v* __restrict__ Z, const int* __restrict__ csr,
    int beg, int end, int c8, float acc[8]) {
    int j = beg;
    for (; j + 4 <= end; j += 4) {               // 4 gathers in flight
        int s0 = csr[j], s1 = csr[j+1], s2 = csr[j+2], s3 = csr[j+3];
        short8v v0 = Z[s0 * 5 + c8];
        short8v v1 = Z[s1 * 5 + c8];
        short8v v2 = Z[s2 * 5 + c8];
        short8v v3 = Z[s3 * 5 + c8];
#pragma unroll
        for (int k = 0; k < 8; ++k)
            acc[k] += (bf2f(v0[k]) + bf2f(v1[k])) + (bf2f(v2[k]) + bf2f(v3[k]));
    }
    for (; j < end; ++j) {
        short8v v = Z[csr[j] * 5 + c8];
#pragma unroll
        for (int k = 0; k < 8; ++k) acc[k] += bf2f(v[k]);
    }
}

// ---- hop1: z1 = bf16( dinv^2 .* (A z0) ), 5 lanes/node -----------------
__global__ __launch_bounds__(TPB) void k_hop1(
    const int* __restrict__ csr, const int* __restrict__ row_ptr,
    const float* __restrict__ dinv, const short* __restrict__ zin,
    short* __restrict__ zout, int N) {
    int t = blockIdx.x * TPB + threadIdx.x;
    int node = t / 5;
    int c8 = t - node * 5;
    if (node >= N) return;
    const short8v* Z = reinterpret_cast<const short8v*>(zin);
    short8v sv = Z[node * 5 + c8];             // self-loop term
    float acc[8];
#pragma unroll
    for (int k = 0; k < 8; ++k) acc[k] = bf2f(sv[k]);
    gather_acc(Z, csr, row_ptr[node], row_ptr[node + 1], c8, acc);
    float dd = dinv[node];
    float sc = dd * dd;
    short8v o;
#pragma unroll
    for (int k = 0; k < 8; ++k) o[k] = f2bf(sc * acc[k]);
    reinterpret_cast<short8v*>(zout)[node * 5 + c8] = o;
}

// ---- hop2 fused with bias + log_softmax --------------------------------
// Wave handles 12 nodes in lanes 0..59 (groups of 5); lanes 60..63 idle.
// out[node] = dinv*(A z1)[node] + b - logsumexp(row).
__global__ __launch_bounds__(TPB) void k_hop2_lsm(
    const int* __restrict__ csr, const int* __restrict__ row_ptr,
    const float* __restrict__ dinv, const short* __restrict__ zin,
    const float* __restrict__ bias, float* __restrict__ out, int N) {
    int wid  = threadIdx.x >> 6;
    int lane = threadIdx.x & 63;
    int g    = lane / 5;
    int c8   = lane - g * 5;
    int node = (blockIdx.x * 4 + wid) * 12 + g;
    bool active = (g < 12) && (node < N);

    float v[8];
    float lm = -1e30f;
    if (active) {
        const short8v* Z = reinterpret_cast<const short8v*>(zin);
        short8v sv = Z[node * 5 + c8];
        float acc[8];
#pragma unroll
        for (int k = 0; k < 8; ++k) acc[k] = bf2f(sv[k]);
        gather_acc(Z, csr, row_ptr[node], row_ptr[node + 1], c8, acc);
        float dd = dinv[node];
#pragma unroll
        for (int k = 0; k < 8; ++k) {
            v[k] = dd * acc[k] + bias[c8 * 8 + k];
            lm = fmaxf(lm, v[k]);
        }
    }
    int base = g * 5;                     // group leader lane (uniform in group)
    float gm = lm;
#pragma unroll
    for (int k = 0; k < 5; ++k) gm = fmaxf(gm, __shfl(lm, base + k, 64));
    float ls = 0.f;
    if (active) {
#pragma unroll
        for (int k = 0; k < 8; ++k) ls += __expf(v[k] - gm);
    }
    float tot = 0.f;
#pragma unroll
    for (int k = 0; k < 5; ++k) tot += __shfl(ls, base + k, 64);
    if (active) {
        float lse = gm + __logf(tot);
        float* op = out + (size_t)node * 40 + c8 * 8;
        *reinterpret_cast<float4*>(op)     = make_float4(v[0]-lse, v[1]-lse, v[2]-lse, v[3]-lse);
        *reinterpret_cast<float4*>(op + 4) = make_float4(v[4]-lse, v[5]-lse, v[6]-lse, v[7]-lse);
    }
}

extern "C" void kernel_launch(void* const* d_in, const int* in_sizes, int n_in,
                              void* d_out, int out_size, void* d_ws, size_t ws_size,
                              hipStream_t stream) {
    const float* x  = (const float*)d_in[0];
    const int*   ei = (const int*)d_in[1];
    const float* W  = (const float*)d_in[2];
    const float* b  = (const float*)d_in[3];
    float* out = (float*)d_out;

    const int N = in_sizes[0] / 512;     // 100000
    const int E = in_sizes[1] / 2;       // 3200000
    const int* src = ei;                 // edge_index[0]
    const int* dst = ei + E;             // edge_index[1]
    const int nb = (N + 255) >> 8;       // 391 buckets

    // workspace: z0b [N*40 bf16] | z1b [N*40 bf16] | csr [E] | pairs [E]
    //   | bcnt [nb] | boff [nb+1] | bcur [nb] | row_ptr [N+1] | dinv [N]
    //   | Wb [48*512 bf16]     (~42 MB total)
    short* z0b     = (short*)d_ws;
    short* z1b     = z0b + (size_t)N * 40;
    int*   csr     = (int*)(z1b + (size_t)N * 40);
    int*   pairs   = csr + E;
    int*   bcnt    = pairs + E;
    int*   boff    = bcnt + nb;
    int*   bcur    = boff + nb + 1;
    int*   row_ptr = bcur + nb;
    float* dinv    = (float*)(row_ptr + N + 1);
    short* Wb      = (short*)(dinv + N);

    int gT  = (E + ETILE - 1) / ETILE;   // 391 edge tiles
    int gM  = (N + 63) / 64;
    int gH1 = (N * 5 + TPB - 1) / TPB;
    int gH2 = (N + 47) / 48;             // 48 nodes per block (12/wave)

    k_wconv<<<(48 * 512) / TPB, TPB, 0, stream>>>(W, Wb, bcnt, nb);
    k_bhist<<<gT, TPB, 0, stream>>>(dst, bcnt, E, nb);
    k_boff<<<1, 512, 0, stream>>>(bcnt, boff, bcur, nb);
    k_part<<<gT, TPB, 0, stream>>>(src, dst, bcur, pairs, E, nb);
    k_sort<<<nb, TPB, 0, stream>>>(pairs, boff, csr, row_ptr, dinv, N, nb);

    k_matmul_mfma<<<gM, TPB, 0, stream>>>(x, Wb, dinv, z0b, N);

    k_hop1<<<gH1, TPB, 0, stream>>>(csr, row_ptr, dinv, z0b, z1b, N);
    k_hop2_lsm<<<gH2, TPB, 0, stream>>>(csr, row_ptr, dinv, z1b, b, out, N);
}